// Round 1
// baseline (11005.044 us; speedup 1.0000x reference)
//
#include <hip/hip_runtime.h>
#include <math.h>

// Problem constants (verified against in_sizes at launch).
constexpr int DH  = 256;
constexpr int DZ  = 128;
constexpr float EPS   = 1e-5f;
constexpr float SLOPE = 0.01f;

// ---------------------------------------------------------------------------
// degree / dinv
// ---------------------------------------------------------------------------
__global__ void deg_count(const int* __restrict__ dst, float* __restrict__ deg, int E) {
    int e = blockIdx.x * blockDim.x + threadIdx.x;
    if (e < E) atomicAdd(&deg[dst[e]], 1.0f);
}

__global__ void make_dinv(float* __restrict__ d, int N) {
    int i = blockIdx.x * blockDim.x + threadIdx.x;
    if (i < N) d[i] = rsqrtf(d[i] + 1.0f);   // +1 self loop
}

// ---------------------------------------------------------------------------
// Tiled fp32 GEMM: C[M,NC] = A[M,K] @ W[K,NC].  64x64 tile, 256 thr, 4x4/thr.
// ---------------------------------------------------------------------------
__global__ __launch_bounds__(256)
void gemm64(const float* __restrict__ A, const float* __restrict__ W,
            float* __restrict__ C, int M, int K, int NC) {
    __shared__ float As[16][65];   // [k][m], +1 pad vs bank conflicts on store
    __shared__ float Ws[16][64];   // [k][n]
    const int tid = threadIdx.x;
    const int bm = blockIdx.x * 64;
    const int bn = blockIdx.y * 64;
    const int tx = tid & 15, ty = tid >> 4;

    const int ar = tid >> 2;          // 0..63 row of A tile
    const int ac = (tid & 3) * 4;     // 0,4,8,12 col (k) of A tile
    const int wr = tid >> 4;          // 0..15 row (k) of W tile
    const int wc = (tid & 15) * 4;    // col of W tile
    const bool arow_ok = (bm + ar) < M;

    float acc[4][4] = {};
    for (int k0 = 0; k0 < K; k0 += 16) {
        float4 av = make_float4(0.f, 0.f, 0.f, 0.f);
        if (arow_ok)
            av = *(const float4*)(A + (size_t)(bm + ar) * K + k0 + ac);
        float4 wv = *(const float4*)(W + (size_t)(k0 + wr) * NC + bn + wc);
        As[ac + 0][ar] = av.x; As[ac + 1][ar] = av.y;
        As[ac + 2][ar] = av.z; As[ac + 3][ar] = av.w;
        *(float4*)&Ws[wr][wc] = wv;
        __syncthreads();
#pragma unroll
        for (int kk = 0; kk < 16; ++kk) {
            float a[4], b[4];
#pragma unroll
            for (int i = 0; i < 4; ++i) a[i] = As[kk][ty * 4 + i];
#pragma unroll
            for (int j = 0; j < 4; ++j) b[j] = Ws[kk][tx * 4 + j];
#pragma unroll
            for (int i = 0; i < 4; ++i)
#pragma unroll
                for (int j = 0; j < 4; ++j) acc[i][j] += a[i] * b[j];
        }
        __syncthreads();
    }
#pragma unroll
    for (int i = 0; i < 4; ++i) {
        int r = bm + ty * 4 + i;
        if (r < M) {
            float4 o = make_float4(acc[i][0], acc[i][1], acc[i][2], acc[i][3]);
            *(float4*)(C + (size_t)r * NC + bn + tx * 4) = o;
        }
    }
}

// ---------------------------------------------------------------------------
// agg = h * dinv^2 (self loop) + bias     (writes every element -> no memset)
// ---------------------------------------------------------------------------
template <int D>
__global__ void agg_init(const float* __restrict__ h, const float* __restrict__ bias,
                         const float* __restrict__ dinv, float* __restrict__ agg, int N) {
    constexpr int D4 = D / 4;
    int idx = blockIdx.x * blockDim.x + threadIdx.x;
    if (idx >= N * D4) return;
    int node = idx / D4;
    int c4 = (idx % D4) * 4;
    float di = dinv[node];
    float s = di * di;
    float4 v = ((const float4*)h)[idx];
    float4 b = *(const float4*)(bias + c4);
    ((float4*)agg)[idx] = make_float4(v.x * s + b.x, v.y * s + b.y,
                                      v.z * s + b.z, v.w * s + b.w);
}

// ---------------------------------------------------------------------------
// edge aggregation: agg[dst] += h[src] * dinv[src]*dinv[dst]
// D/4 lanes per edge; each lane a float4 -> 1KiB coalesced row read per edge.
// ---------------------------------------------------------------------------
template <int D>
__global__ void agg_edges(const float* __restrict__ h, const int* __restrict__ src,
                          const int* __restrict__ dst, const float* __restrict__ dinv,
                          float* __restrict__ agg, int E) {
    constexpr int LPE = D / 4;
    int t = blockIdx.x * blockDim.x + threadIdx.x;
    int e = t / LPE;
    int l = t % LPE;
    if (e >= E) return;
    int s = src[e], d = dst[e];
    float nrm = dinv[s] * dinv[d];
    float4 v = ((const float4*)(h + (size_t)s * D))[l];
    float* out = agg + (size_t)d * D + l * 4;
    atomicAdd(out + 0, v.x * nrm);
    atomicAdd(out + 1, v.y * nrm);
    atomicAdd(out + 2, v.z * nrm);
    atomicAdd(out + 3, v.w * nrm);
}

// ---------------------------------------------------------------------------
// graph-wide LayerNorm: sum & sumsq over all N*D elements
// ---------------------------------------------------------------------------
__global__ void ln_reduce(const float* __restrict__ x, double* __restrict__ sums, int total4) {
    float s = 0.f, q = 0.f;
    for (int i = blockIdx.x * blockDim.x + threadIdx.x; i < total4;
         i += gridDim.x * blockDim.x) {
        float4 v = ((const float4*)x)[i];
        s += v.x + v.y + v.z + v.w;
        q += v.x * v.x + v.y * v.y + v.z * v.z + v.w * v.w;
    }
#pragma unroll
    for (int off = 32; off; off >>= 1) {
        s += __shfl_down(s, off);
        q += __shfl_down(q, off);
    }
    __shared__ float ss[4], qq[4];
    int wid = threadIdx.x >> 6, lane = threadIdx.x & 63;
    if (lane == 0) { ss[wid] = s; qq[wid] = q; }
    __syncthreads();
    if (threadIdx.x == 0) {
        atomicAdd(&sums[0], (double)(ss[0] + ss[1] + ss[2] + ss[3]));
        atomicAdd(&sums[1], (double)(qq[0] + qq[1] + qq[2] + qq[3]));
    }
}

__global__ void ln_finalize(const double* __restrict__ sums, float* __restrict__ scl, double M) {
    double mu  = sums[0] / M;
    double var = sums[1] / M - mu * mu;
    if (var < 0.0) var = 0.0;
    float sd = (float)sqrt(var);
    scl[0] = (float)mu;
    scl[1] = 1.0f / (sd + EPS);
}

template <int D>
__global__ void ln_apply(const float* __restrict__ x, const float* __restrict__ gamma,
                         const float* __restrict__ beta, const float* __restrict__ scl,
                         float* __restrict__ y, int N) {
    constexpr int D4 = D / 4;
    int idx = blockIdx.x * blockDim.x + threadIdx.x;
    if (idx >= N * D4) return;
    float mean = scl[0], inv = scl[1];
    int c4 = (idx % D4) * 4;
    float4 v = ((const float4*)x)[idx];
    float4 g = *(const float4*)(gamma + c4);
    float4 b = *(const float4*)(beta + c4);
    float o0 = (v.x - mean) * inv * g.x + b.x;
    float o1 = (v.y - mean) * inv * g.y + b.y;
    float o2 = (v.z - mean) * inv * g.z + b.z;
    float o3 = (v.w - mean) * inv * g.w + b.w;
    o0 = o0 > 0.f ? o0 : SLOPE * o0;
    o1 = o1 > 0.f ? o1 : SLOPE * o1;
    o2 = o2 > 0.f ? o2 : SLOPE * o2;
    o3 = o3 > 0.f ? o3 : SLOPE * o3;
    ((float4*)y)[idx] = make_float4(o0, o1, o2, o3);
}

// ---------------------------------------------------------------------------
// launcher
// ---------------------------------------------------------------------------
extern "C" void kernel_launch(void* const* d_in, const int* in_sizes, int n_in,
                              void* d_out, int out_size, void* d_ws, size_t ws_size,
                              hipStream_t stream) {
    const float* x   = (const float*)d_in[0];
    const int*   ei  = (const int*)d_in[1];
    const float* W1  = (const float*)d_in[2];
    const float* b1  = (const float*)d_in[3];
    const float* g1  = (const float*)d_in[4];
    const float* be1 = (const float*)d_in[5];
    const float* W2  = (const float*)d_in[6];
    const float* b2  = (const float*)d_in[7];
    const float* g2  = (const float*)d_in[8];
    const float* be2 = (const float*)d_in[9];
    const float* W3  = (const float*)d_in[10];
    const float* b3  = (const float*)d_in[11];
    const float* g3  = (const float*)d_in[12];
    const float* be3 = (const float*)d_in[13];
    const float* W4  = (const float*)d_in[14];
    const float* b4  = (const float*)d_in[15];

    const int N = in_sizes[0] / DH;   // 100000
    const int E = in_sizes[1] / 2;    // 800000
    const int* src = ei;
    const int* dst = ei + E;

    // workspace layout (~196 MB needed)
    char* w = (char*)d_ws;
    float* dinv = (float*)w;
    size_t off = ((size_t)N * sizeof(float) + 15) & ~(size_t)15;
    double* sums = (double*)(w + off); off += 16;
    float*  scl  = (float*)(w + off);  off += 16;
    float* bufA = (float*)(w + off);   off += (size_t)N * DH * sizeof(float);
    float* bufB = (float*)(w + off);

    // degree -> dinv
    hipMemsetAsync(dinv, 0, N * sizeof(float), stream);
    deg_count<<<(E + 255) / 256, 256, 0, stream>>>(dst, dinv, E);
    make_dinv<<<(N + 255) / 256, 256, 0, stream>>>(dinv, N);

    auto layer = [&](const float* act_in, const float* W, const float* b,
                     const float* g, const float* be, float* h, float* agg,
                     float* act_out) {
        gemm64<<<dim3((N + 63) / 64, DH / 64), 256, 0, stream>>>(act_in, W, h, N, DH, DH);
        int t4 = N * (DH / 4);
        agg_init<DH><<<(t4 + 255) / 256, 256, 0, stream>>>(h, b, dinv, agg, N);
        int et = E * (DH / 4);
        agg_edges<DH><<<(et + 255) / 256, 256, 0, stream>>>(h, src, dst, dinv, agg, E);
        hipMemsetAsync(sums, 0, 2 * sizeof(double), stream);
        ln_reduce<<<1024, 256, 0, stream>>>(agg, sums, t4);
        ln_finalize<<<1, 1, 0, stream>>>(sums, scl, (double)N * DH);
        ln_apply<DH><<<(t4 + 255) / 256, 256, 0, stream>>>(agg, g, be, scl, act_out, N);
    };

    // ping-pong: (in, h, agg, out)
    layer(x,    W1, b1, g1, be1, bufA, bufB, bufA);   // act1 in bufA
    layer(bufA, W2, b2, g2, be2, bufB, bufA, bufB);   // act2 in bufB
    layer(bufB, W3, b3, g3, be3, bufA, bufB, bufA);   // act3 in bufA

    // final conv: DH -> DZ, output straight to d_out
    float* h4 = bufB;
    gemm64<<<dim3((N + 63) / 64, DZ / 64), 256, 0, stream>>>(bufA, W4, h4, N, DH, DZ);
    float* out = (float*)d_out;
    int t4z = N * (DZ / 4);
    agg_init<DZ><<<(t4z + 255) / 256, 256, 0, stream>>>(h4, b4, dinv, out, N);
    int etz = E * (DZ / 4);
    agg_edges<DZ><<<(etz + 255) / 256, 256, 0, stream>>>(h4, src, dst, dinv, out, E);
}

// Round 2
// 1581.403 us; speedup vs baseline: 6.9590x; 6.9590x over previous
//
#include <hip/hip_runtime.h>
#include <math.h>

constexpr int DH  = 256;
constexpr int DZ  = 128;
constexpr float EPS   = 1e-5f;
constexpr float SLOPE = 0.01f;

// ---------------------------------------------------------------------------
// degree (int) / dinv
// ---------------------------------------------------------------------------
__global__ void deg_count_i(const int* __restrict__ dst, int* __restrict__ deg, int E) {
    int e = blockIdx.x * blockDim.x + threadIdx.x;
    if (e < E) atomicAdd(&deg[dst[e]], 1);
}

__global__ void make_dinv(const int* __restrict__ deg, float* __restrict__ dinv, int N) {
    int i = blockIdx.x * blockDim.x + threadIdx.x;
    if (i < N) dinv[i] = rsqrtf((float)deg[i] + 1.0f);   // +1 self loop
}

// ---------------------------------------------------------------------------
// exclusive scan of deg[N] -> rowptr[N] (+ rowptr[N]=E), 1024 elems/block
// ---------------------------------------------------------------------------
__global__ __launch_bounds__(256)
void scan1(const int* __restrict__ deg, int* __restrict__ rowptr,
           int* __restrict__ blocksum, int N) {
    __shared__ int ts[256];
    int base = blockIdx.x * 1024 + threadIdx.x * 4;
    int v[4], s = 0;
#pragma unroll
    for (int i = 0; i < 4; ++i) {
        v[i] = (base + i < N) ? deg[base + i] : 0;
        s += v[i];
    }
    ts[threadIdx.x] = s;
    __syncthreads();
    for (int off = 1; off < 256; off <<= 1) {
        int t = 0;
        if ((int)threadIdx.x >= off) t = ts[threadIdx.x - off];
        __syncthreads();
        if ((int)threadIdx.x >= off) ts[threadIdx.x] += t;
        __syncthreads();
    }
    int run = ts[threadIdx.x] - s;   // exclusive prefix of this thread
#pragma unroll
    for (int i = 0; i < 4; ++i) {
        if (base + i < N) rowptr[base + i] = run;
        run += v[i];
    }
    if (threadIdx.x == 255) blocksum[blockIdx.x] = ts[255];
}

__global__ __launch_bounds__(256)
void scan2(const int* __restrict__ blocksum, int* __restrict__ blockoff,
           int nb, int* __restrict__ rowptr_last) {
    __shared__ int ts[256];
    int v = ((int)threadIdx.x < nb) ? blocksum[threadIdx.x] : 0;
    ts[threadIdx.x] = v;
    __syncthreads();
    for (int off = 1; off < 256; off <<= 1) {
        int t = 0;
        if ((int)threadIdx.x >= off) t = ts[threadIdx.x - off];
        __syncthreads();
        if ((int)threadIdx.x >= off) ts[threadIdx.x] += t;
        __syncthreads();
    }
    blockoff[threadIdx.x] = ts[threadIdx.x] - v;   // exclusive
    if (threadIdx.x == 255) *rowptr_last = ts[255];  // == E
}

__global__ void scan3(int* __restrict__ rowptr, const int* __restrict__ blockoff, int N) {
    int i = blockIdx.x * blockDim.x + threadIdx.x;
    if (i < N) rowptr[i] += blockoff[i >> 10];
}

// fill[d] must be zeroed; csr_src gets the sources of each node's in-edges
__global__ void csr_fill(const int* __restrict__ src, const int* __restrict__ dst,
                         const int* __restrict__ rowptr, int* __restrict__ fill,
                         int* __restrict__ csr_src, int E) {
    int e = blockIdx.x * blockDim.x + threadIdx.x;
    if (e >= E) return;
    int d = dst[e];
    int pos = rowptr[d] + atomicAdd(&fill[d], 1);
    csr_src[pos] = src[e];
}

// ---------------------------------------------------------------------------
// Tiled fp32 GEMM: C[M,NC] = A[M,K] @ W[K,NC].  64x64 tile, 256 thr, 4x4/thr.
// ---------------------------------------------------------------------------
__global__ __launch_bounds__(256)
void gemm64(const float* __restrict__ A, const float* __restrict__ W,
            float* __restrict__ C, int M, int K, int NC) {
    __shared__ float As[16][65];
    __shared__ float Ws[16][64];
    const int tid = threadIdx.x;
    const int bm = blockIdx.x * 64;
    const int bn = blockIdx.y * 64;
    const int tx = tid & 15, ty = tid >> 4;

    const int ar = tid >> 2;
    const int ac = (tid & 3) * 4;
    const int wr = tid >> 4;
    const int wc = (tid & 15) * 4;
    const bool arow_ok = (bm + ar) < M;

    float acc[4][4] = {};
    for (int k0 = 0; k0 < K; k0 += 16) {
        float4 av = make_float4(0.f, 0.f, 0.f, 0.f);
        if (arow_ok)
            av = *(const float4*)(A + (size_t)(bm + ar) * K + k0 + ac);
        float4 wv = *(const float4*)(W + (size_t)(k0 + wr) * NC + bn + wc);
        As[ac + 0][ar] = av.x; As[ac + 1][ar] = av.y;
        As[ac + 2][ar] = av.z; As[ac + 3][ar] = av.w;
        *(float4*)&Ws[wr][wc] = wv;
        __syncthreads();
#pragma unroll
        for (int kk = 0; kk < 16; ++kk) {
            float a[4], b[4];
#pragma unroll
            for (int i = 0; i < 4; ++i) a[i] = As[kk][ty * 4 + i];
#pragma unroll
            for (int j = 0; j < 4; ++j) b[j] = Ws[kk][tx * 4 + j];
#pragma unroll
            for (int i = 0; i < 4; ++i)
#pragma unroll
                for (int j = 0; j < 4; ++j) acc[i][j] += a[i] * b[j];
        }
        __syncthreads();
    }
#pragma unroll
    for (int i = 0; i < 4; ++i) {
        int r = bm + ty * 4 + i;
        if (r < M) {
            float4 o = make_float4(acc[i][0], acc[i][1], acc[i][2], acc[i][3]);
            *(float4*)(C + (size_t)r * NC + bn + tx * 4) = o;
        }
    }
}

// ---------------------------------------------------------------------------
// CSR aggregation, fused self-loop + bias:
//   agg[n] = h[n]*dinv[n]^2 + bias + sum_{s in inlist(n)} h[s]*dinv[s]*dinv[n]
// One D/4-lane group per node; each lane owns one float4 of the row.
// ---------------------------------------------------------------------------
template <int D>
__global__ __launch_bounds__(256)
void agg_csr(const float* __restrict__ h, const int* __restrict__ rowptr,
             const int* __restrict__ csr_src, const float* __restrict__ dinv,
             const float* __restrict__ bias, float* __restrict__ agg, int N) {
    constexpr int TPN = D / 4;
    int t = blockIdx.x * blockDim.x + threadIdx.x;
    int n = t / TPN;
    int l = t % TPN;
    if (n >= N) return;
    const float4* h4 = (const float4*)h;
    float di = dinv[n];
    float s2 = di * di;
    float4 acc = h4[(size_t)n * TPN + l];
    float4 b = ((const float4*)bias)[l];
    acc.x = acc.x * s2 + b.x;
    acc.y = acc.y * s2 + b.y;
    acc.z = acc.z * s2 + b.z;
    acc.w = acc.w * s2 + b.w;
    int j = rowptr[n], j1 = rowptr[n + 1];
    // 2x unroll for load ILP
    for (; j + 1 < j1; j += 2) {
        int sA = csr_src[j], sB = csr_src[j + 1];
        float wA = dinv[sA] * di, wB = dinv[sB] * di;
        float4 vA = h4[(size_t)sA * TPN + l];
        float4 vB = h4[(size_t)sB * TPN + l];
        acc.x += vA.x * wA + vB.x * wB;
        acc.y += vA.y * wA + vB.y * wB;
        acc.z += vA.z * wA + vB.z * wB;
        acc.w += vA.w * wA + vB.w * wB;
    }
    if (j < j1) {
        int s = csr_src[j];
        float w = dinv[s] * di;
        float4 v = h4[(size_t)s * TPN + l];
        acc.x += v.x * w; acc.y += v.y * w; acc.z += v.z * w; acc.w += v.w * w;
    }
    ((float4*)agg)[(size_t)n * TPN + l] = acc;
}

// ---------------------------------------------------------------------------
// graph-wide LayerNorm
// ---------------------------------------------------------------------------
__global__ void ln_reduce(const float* __restrict__ x, double* __restrict__ sums, int total4) {
    float s = 0.f, q = 0.f;
    for (int i = blockIdx.x * blockDim.x + threadIdx.x; i < total4;
         i += gridDim.x * blockDim.x) {
        float4 v = ((const float4*)x)[i];
        s += v.x + v.y + v.z + v.w;
        q += v.x * v.x + v.y * v.y + v.z * v.z + v.w * v.w;
    }
#pragma unroll
    for (int off = 32; off; off >>= 1) {
        s += __shfl_down(s, off);
        q += __shfl_down(q, off);
    }
    __shared__ float ss[4], qq[4];
    int wid = threadIdx.x >> 6, lane = threadIdx.x & 63;
    if (lane == 0) { ss[wid] = s; qq[wid] = q; }
    __syncthreads();
    if (threadIdx.x == 0) {
        atomicAdd(&sums[0], (double)(ss[0] + ss[1] + ss[2] + ss[3]));
        atomicAdd(&sums[1], (double)(qq[0] + qq[1] + qq[2] + qq[3]));
    }
}

__global__ void ln_finalize(const double* __restrict__ sums, float* __restrict__ scl, double M) {
    double mu  = sums[0] / M;
    double var = sums[1] / M - mu * mu;
    if (var < 0.0) var = 0.0;
    float sd = (float)sqrt(var);
    scl[0] = (float)mu;
    scl[1] = 1.0f / (sd + EPS);
}

template <int D>
__global__ void ln_apply(const float* __restrict__ x, const float* __restrict__ gamma,
                         const float* __restrict__ beta, const float* __restrict__ scl,
                         float* __restrict__ y, int N) {
    constexpr int D4 = D / 4;
    int idx = blockIdx.x * blockDim.x + threadIdx.x;
    if (idx >= N * D4) return;
    float mean = scl[0], inv = scl[1];
    int c4 = (idx % D4) * 4;
    float4 v = ((const float4*)x)[idx];
    float4 g = *(const float4*)(gamma + c4);
    float4 b = *(const float4*)(beta + c4);
    float o0 = (v.x - mean) * inv * g.x + b.x;
    float o1 = (v.y - mean) * inv * g.y + b.y;
    float o2 = (v.z - mean) * inv * g.z + b.z;
    float o3 = (v.w - mean) * inv * g.w + b.w;
    o0 = o0 > 0.f ? o0 : SLOPE * o0;
    o1 = o1 > 0.f ? o1 : SLOPE * o1;
    o2 = o2 > 0.f ? o2 : SLOPE * o2;
    o3 = o3 > 0.f ? o3 : SLOPE * o3;
    ((float4*)y)[idx] = make_float4(o0, o1, o2, o3);
}

// ---------------------------------------------------------------------------
// launcher
// ---------------------------------------------------------------------------
extern "C" void kernel_launch(void* const* d_in, const int* in_sizes, int n_in,
                              void* d_out, int out_size, void* d_ws, size_t ws_size,
                              hipStream_t stream) {
    const float* x   = (const float*)d_in[0];
    const int*   ei  = (const int*)d_in[1];
    const float* W1  = (const float*)d_in[2];
    const float* b1  = (const float*)d_in[3];
    const float* g1  = (const float*)d_in[4];
    const float* be1 = (const float*)d_in[5];
    const float* W2  = (const float*)d_in[6];
    const float* b2  = (const float*)d_in[7];
    const float* g2  = (const float*)d_in[8];
    const float* be2 = (const float*)d_in[9];
    const float* W3  = (const float*)d_in[10];
    const float* b3  = (const float*)d_in[11];
    const float* g3  = (const float*)d_in[12];
    const float* be3 = (const float*)d_in[13];
    const float* W4  = (const float*)d_in[14];
    const float* b4  = (const float*)d_in[15];

    const int N = in_sizes[0] / DH;   // 100000
    const int E = in_sizes[1] / 2;    // 800000
    const int* src = ei;
    const int* dst = ei + E;
    const int nb = (N + 1023) / 1024; // scan blocks (98)

    // workspace layout
    char* w = (char*)d_ws;
    size_t off = 0;
    auto alloc = [&](size_t bytes) { char* p = w + off; off = (off + bytes + 255) & ~(size_t)255; return p; };
    int*    deg      = (int*)alloc((size_t)N * 4);        // reused as `fill` later
    int*    rowptr   = (int*)alloc((size_t)(N + 1) * 4);
    int*    blocksum = (int*)alloc(256 * 4);
    int*    blockoff = (int*)alloc(256 * 4);
    float*  dinv     = (float*)alloc((size_t)N * 4);
    double* sums     = (double*)alloc(64);
    float*  scl      = (float*)alloc(64);
    int*    csr_src  = (int*)alloc((size_t)E * 4);
    float*  bufA     = (float*)alloc((size_t)N * DH * 4);
    float*  bufB     = (float*)alloc((size_t)N * DH * 4);

    // ---- degree, dinv, CSR build ----
    hipMemsetAsync(deg, 0, (size_t)N * 4, stream);
    deg_count_i<<<(E + 255) / 256, 256, 0, stream>>>(dst, deg, E);
    make_dinv<<<(N + 255) / 256, 256, 0, stream>>>(deg, dinv, N);
    scan1<<<nb, 256, 0, stream>>>(deg, rowptr, blocksum, N);
    scan2<<<1, 256, 0, stream>>>(blocksum, blockoff, nb, rowptr + N);
    scan3<<<(N + 255) / 256, 256, 0, stream>>>(rowptr, blockoff, N);
    hipMemsetAsync(deg, 0, (size_t)N * 4, stream);   // reuse as fill counters
    csr_fill<<<(E + 255) / 256, 256, 0, stream>>>(src, dst, rowptr, deg, csr_src, E);

    auto layer = [&](const float* act_in, const float* W, const float* b,
                     const float* g, const float* be, float* h, float* agg,
                     float* act_out) {
        gemm64<<<dim3((N + 63) / 64, DH / 64), 256, 0, stream>>>(act_in, W, h, N, DH, DH);
        int gt = N * (DH / 4);
        agg_csr<DH><<<(gt + 255) / 256, 256, 0, stream>>>(h, rowptr, csr_src, dinv, b, agg, N);
        hipMemsetAsync(sums, 0, 2 * sizeof(double), stream);
        ln_reduce<<<1024, 256, 0, stream>>>(agg, sums, gt);
        ln_finalize<<<1, 1, 0, stream>>>(sums, scl, (double)N * DH);
        ln_apply<DH><<<(gt + 255) / 256, 256, 0, stream>>>(agg, g, be, scl, act_out, N);
    };

    layer(x,    W1, b1, g1, be1, bufA, bufB, bufA);
    layer(bufA, W2, b2, g2, be2, bufB, bufA, bufB);
    layer(bufB, W3, b3, g3, be3, bufA, bufB, bufA);

    // final conv: DH -> DZ, straight to d_out
    float* h4 = bufB;
    gemm64<<<dim3((N + 63) / 64, DZ / 64), 256, 0, stream>>>(bufA, W4, h4, N, DH, DZ);
    float* out = (float*)d_out;
    int gtz = N * (DZ / 4);
    agg_csr<DZ><<<(gtz + 255) / 256, 256, 0, stream>>>(h4, rowptr, csr_src, dinv, b4, out, N);
}

// Round 3
// 1093.809 us; speedup vs baseline: 10.0612x; 1.4458x over previous
//
#include <hip/hip_runtime.h>
#include <math.h>

constexpr int DH  = 256;
constexpr int DZ  = 128;
constexpr float EPS   = 1e-5f;
constexpr float SLOPE = 0.01f;

typedef __attribute__((ext_vector_type(8))) short bf16x8;
typedef __attribute__((ext_vector_type(4))) float f32x4;

__device__ __forceinline__ short f2bf(float f) {
    union { float f; unsigned u; } v; v.f = f;
    unsigned r = v.u + 0x7fffu + ((v.u >> 16) & 1u);   // RNE
    return (short)(r >> 16);
}

// ---------------------------------------------------------------------------
// degree (int) / dinv
// ---------------------------------------------------------------------------
__global__ void deg_count_i(const int* __restrict__ dst, int* __restrict__ deg, int E) {
    int e = blockIdx.x * blockDim.x + threadIdx.x;
    if (e < E) atomicAdd(&deg[dst[e]], 1);
}

__global__ void make_dinv(const int* __restrict__ deg, float* __restrict__ dinv, int N) {
    int i = blockIdx.x * blockDim.x + threadIdx.x;
    if (i < N) dinv[i] = rsqrtf((float)deg[i] + 1.0f);
}

// ---------------------------------------------------------------------------
// exclusive scan of deg[N] -> rowptr
// ---------------------------------------------------------------------------
__global__ __launch_bounds__(256)
void scan1(const int* __restrict__ deg, int* __restrict__ rowptr,
           int* __restrict__ blocksum, int N) {
    __shared__ int ts[256];
    int base = blockIdx.x * 1024 + threadIdx.x * 4;
    int v[4], s = 0;
#pragma unroll
    for (int i = 0; i < 4; ++i) {
        v[i] = (base + i < N) ? deg[base + i] : 0;
        s += v[i];
    }
    ts[threadIdx.x] = s;
    __syncthreads();
    for (int off = 1; off < 256; off <<= 1) {
        int t = 0;
        if ((int)threadIdx.x >= off) t = ts[threadIdx.x - off];
        __syncthreads();
        if ((int)threadIdx.x >= off) ts[threadIdx.x] += t;
        __syncthreads();
    }
    int run = ts[threadIdx.x] - s;
#pragma unroll
    for (int i = 0; i < 4; ++i) {
        if (base + i < N) rowptr[base + i] = run;
        run += v[i];
    }
    if (threadIdx.x == 255) blocksum[blockIdx.x] = ts[255];
}

__global__ __launch_bounds__(256)
void scan2(const int* __restrict__ blocksum, int* __restrict__ blockoff,
           int nb, int* __restrict__ rowptr_last) {
    __shared__ int ts[256];
    int v = ((int)threadIdx.x < nb) ? blocksum[threadIdx.x] : 0;
    ts[threadIdx.x] = v;
    __syncthreads();
    for (int off = 1; off < 256; off <<= 1) {
        int t = 0;
        if ((int)threadIdx.x >= off) t = ts[threadIdx.x - off];
        __syncthreads();
        if ((int)threadIdx.x >= off) ts[threadIdx.x] += t;
        __syncthreads();
    }
    blockoff[threadIdx.x] = ts[threadIdx.x] - v;
    if (threadIdx.x == 255) *rowptr_last = ts[255];
}

__global__ void scan3(int* __restrict__ rowptr, const int* __restrict__ blockoff, int N) {
    int i = blockIdx.x * blockDim.x + threadIdx.x;
    if (i < N) rowptr[i] += blockoff[i >> 10];
}

__global__ void csr_fill(const int* __restrict__ src, const int* __restrict__ dst,
                         const int* __restrict__ rowptr, int* __restrict__ fill,
                         int* __restrict__ csr_src, int E) {
    int e = blockIdx.x * blockDim.x + threadIdx.x;
    if (e >= E) return;
    int d = dst[e];
    int pos = rowptr[d] + atomicAdd(&fill[d], 1);
    csr_src[pos] = src[e];
}

// ---------------------------------------------------------------------------
// casts: x -> bf16 ; W[K][N] -> Wt[N][K] bf16
// ---------------------------------------------------------------------------
__global__ void cast_bf16(const float* __restrict__ x, short* __restrict__ y, int n4) {
    int i = blockIdx.x * blockDim.x + threadIdx.x;
    if (i >= n4) return;
    float4 v = ((const float4*)x)[i];
    short4 o;
    o.x = f2bf(v.x); o.y = f2bf(v.y); o.z = f2bf(v.z); o.w = f2bf(v.w);
    ((short4*)y)[i] = o;
}

__global__ void wt_cast(const float* __restrict__ W, short* __restrict__ Wt, int K, int NC) {
    int idx = blockIdx.x * blockDim.x + threadIdx.x;   // over NC*K, output-linear
    if (idx >= K * NC) return;
    int n = idx / K, k = idx % K;
    Wt[idx] = f2bf(W[k * NC + n]);
}

// ---------------------------------------------------------------------------
// bf16 MFMA GEMM (m97 structure): C[M,NC] = A[M,K] @ Wt[NC,K]^T
// 128x128 tile, 4 waves (2x2), 16x16x32 MFMA, 4x4 frags/wave, BK=32,
// global_load_lds width=16 staging.
// ---------------------------------------------------------------------------
__global__ __launch_bounds__(256)
void gemm_mfma(const short* __restrict__ A, const short* __restrict__ Bt,
               float* __restrict__ C, int M, int K, int NC) {
    __shared__ short As[128 * 32];
    __shared__ short Bs[128 * 32];
    const int tid  = threadIdx.x;
    const int lane = tid & 63;
    const int w    = tid >> 6;        // wave 0..3
    const int wm   = w & 1, wn = w >> 1;
    const int bm   = blockIdx.x * 128;
    const int bn   = blockIdx.y * 128;

    // staging coords: each wave stages 16 rows per chunk, lane -> (row, 8-col)
    const int srow = w * 16 + (lane >> 2);     // tile row, chunk0 (chunk1 = +64)
    const int scol = (lane & 3) * 8;           // bf16 col within BK

    const int ga_r0 = (bm + srow      < M) ? bm + srow      : M - 1;
    const int ga_r1 = (bm + srow + 64 < M) ? bm + srow + 64 : M - 1;
    const size_t arow0 = (size_t)ga_r0 * K;
    const size_t arow1 = (size_t)ga_r1 * K;
    const size_t brow0 = (size_t)(bn + srow) * K;
    const size_t brow1 = (size_t)(bn + srow + 64) * K;

    f32x4 acc[4][4];
#pragma unroll
    for (int i = 0; i < 4; ++i)
#pragma unroll
        for (int j = 0; j < 4; ++j) acc[i][j] = (f32x4){0.f, 0.f, 0.f, 0.f};

    const int frow = lane & 15;       // fragment row/col within 16-tile
    const int kg   = (lane >> 4) * 8; // k-group offset

    for (int k0 = 0; k0 < K; k0 += 32) {
        __syncthreads();   // previous iteration's ds_reads done
        __builtin_amdgcn_global_load_lds(
            (const __attribute__((address_space(1))) void*)(A + arow0 + k0 + scol),
            (__attribute__((address_space(3))) void*)&As[srow * 32 + scol], 16, 0, 0);
        __builtin_amdgcn_global_load_lds(
            (const __attribute__((address_space(1))) void*)(A + arow1 + k0 + scol),
            (__attribute__((address_space(3))) void*)&As[(srow + 64) * 32 + scol], 16, 0, 0);
        __builtin_amdgcn_global_load_lds(
            (const __attribute__((address_space(1))) void*)(Bt + brow0 + k0 + scol),
            (__attribute__((address_space(3))) void*)&Bs[srow * 32 + scol], 16, 0, 0);
        __builtin_amdgcn_global_load_lds(
            (const __attribute__((address_space(1))) void*)(Bt + brow1 + k0 + scol),
            (__attribute__((address_space(3))) void*)&Bs[(srow + 64) * 32 + scol], 16, 0, 0);
        __syncthreads();   // staging drained (vmcnt(0) before barrier)

        bf16x8 af[4], bf[4];
#pragma unroll
        for (int i = 0; i < 4; ++i)
            af[i] = *(const bf16x8*)&As[(wm * 64 + i * 16 + frow) * 32 + kg];
#pragma unroll
        for (int j = 0; j < 4; ++j)
            bf[j] = *(const bf16x8*)&Bs[(wn * 64 + j * 16 + frow) * 32 + kg];
#pragma unroll
        for (int i = 0; i < 4; ++i)
#pragma unroll
            for (int j = 0; j < 4; ++j)
                acc[i][j] = __builtin_amdgcn_mfma_f32_16x16x32_bf16(
                    af[i], bf[j], acc[i][j], 0, 0, 0);
    }

    // epilogue: C/D layout col=lane&15, row=(lane>>4)*4+reg
    const int row_base = bm + wm * 64 + (lane >> 4) * 4;
    const int col_base = bn + wn * 64 + (lane & 15);
#pragma unroll
    for (int i = 0; i < 4; ++i) {
#pragma unroll
        for (int r = 0; r < 4; ++r) {
            int row = row_base + i * 16 + r;
            if (row < M) {
                float* cp = C + (size_t)row * NC + col_base;
#pragma unroll
                for (int j = 0; j < 4; ++j) cp[j * 16] = acc[i][j][r];
            }
        }
    }
}

// ---------------------------------------------------------------------------
// CSR aggregation, fused self-loop + bias (h fp32)
// ---------------------------------------------------------------------------
template <int D>
__global__ __launch_bounds__(256)
void agg_csr(const float* __restrict__ h, const int* __restrict__ rowptr,
             const int* __restrict__ csr_src, const float* __restrict__ dinv,
             const float* __restrict__ bias, float* __restrict__ agg, int N) {
    constexpr int TPN = D / 4;
    int t = blockIdx.x * blockDim.x + threadIdx.x;
    int n = t / TPN;
    int l = t % TPN;
    if (n >= N) return;
    const float4* h4 = (const float4*)h;
    float di = dinv[n];
    float s2 = di * di;
    float4 acc = h4[(size_t)n * TPN + l];
    float4 b = ((const float4*)bias)[l];
    acc.x = acc.x * s2 + b.x;
    acc.y = acc.y * s2 + b.y;
    acc.z = acc.z * s2 + b.z;
    acc.w = acc.w * s2 + b.w;
    int j = rowptr[n], j1 = rowptr[n + 1];
    for (; j + 1 < j1; j += 2) {
        int sA = csr_src[j], sB = csr_src[j + 1];
        float wA = dinv[sA] * di, wB = dinv[sB] * di;
        float4 vA = h4[(size_t)sA * TPN + l];
        float4 vB = h4[(size_t)sB * TPN + l];
        acc.x += vA.x * wA + vB.x * wB;
        acc.y += vA.y * wA + vB.y * wB;
        acc.z += vA.z * wA + vB.z * wB;
        acc.w += vA.w * wA + vB.w * wB;
    }
    if (j < j1) {
        int s = csr_src[j];
        float wgt = dinv[s] * di;
        float4 v = h4[(size_t)s * TPN + l];
        acc.x += v.x * wgt; acc.y += v.y * wgt; acc.z += v.z * wgt; acc.w += v.w * wgt;
    }
    ((float4*)agg)[(size_t)n * TPN + l] = acc;
}

// ---------------------------------------------------------------------------
// graph-wide LayerNorm
// ---------------------------------------------------------------------------
__global__ void ln_reduce(const float* __restrict__ x, double* __restrict__ sums, int total4) {
    float s = 0.f, q = 0.f;
    for (int i = blockIdx.x * blockDim.x + threadIdx.x; i < total4;
         i += gridDim.x * blockDim.x) {
        float4 v = ((const float4*)x)[i];
        s += v.x + v.y + v.z + v.w;
        q += v.x * v.x + v.y * v.y + v.z * v.z + v.w * v.w;
    }
#pragma unroll
    for (int off = 32; off; off >>= 1) {
        s += __shfl_down(s, off);
        q += __shfl_down(q, off);
    }
    __shared__ float ss[4], qq[4];
    int wid = threadIdx.x >> 6, lane = threadIdx.x & 63;
    if (lane == 0) { ss[wid] = s; qq[wid] = q; }
    __syncthreads();
    if (threadIdx.x == 0) {
        atomicAdd(&sums[0], (double)(ss[0] + ss[1] + ss[2] + ss[3]));
        atomicAdd(&sums[1], (double)(qq[0] + qq[1] + qq[2] + qq[3]));
    }
}

__global__ void ln_finalize(const double* __restrict__ sums, float* __restrict__ scl, double M) {
    double mu  = sums[0] / M;
    double var = sums[1] / M - mu * mu;
    if (var < 0.0) var = 0.0;
    float sd = (float)sqrt(var);
    scl[0] = (float)mu;
    scl[1] = 1.0f / (sd + EPS);
}

// ln_apply + leaky_relu, emits bf16 activations for the next GEMM
template <int D>
__global__ void ln_apply_bf(const float* __restrict__ x, const float* __restrict__ gamma,
                            const float* __restrict__ beta, const float* __restrict__ scl,
                            short* __restrict__ y, int N) {
    constexpr int D4 = D / 4;
    int idx = blockIdx.x * blockDim.x + threadIdx.x;
    if (idx >= N * D4) return;
    float mean = scl[0], inv = scl[1];
    int c4 = (idx % D4) * 4;
    float4 v = ((const float4*)x)[idx];
    float4 g = *(const float4*)(gamma + c4);
    float4 b = *(const float4*)(beta + c4);
    float o0 = (v.x - mean) * inv * g.x + b.x;
    float o1 = (v.y - mean) * inv * g.y + b.y;
    float o2 = (v.z - mean) * inv * g.z + b.z;
    float o3 = (v.w - mean) * inv * g.w + b.w;
    o0 = o0 > 0.f ? o0 : SLOPE * o0;
    o1 = o1 > 0.f ? o1 : SLOPE * o1;
    o2 = o2 > 0.f ? o2 : SLOPE * o2;
    o3 = o3 > 0.f ? o3 : SLOPE * o3;
    short4 o;
    o.x = f2bf(o0); o.y = f2bf(o1); o.z = f2bf(o2); o.w = f2bf(o3);
    ((short4*)y)[idx] = o;
}

// ---------------------------------------------------------------------------
// launcher
// ---------------------------------------------------------------------------
extern "C" void kernel_launch(void* const* d_in, const int* in_sizes, int n_in,
                              void* d_out, int out_size, void* d_ws, size_t ws_size,
                              hipStream_t stream) {
    const float* x   = (const float*)d_in[0];
    const int*   ei  = (const int*)d_in[1];
    const float* W1  = (const float*)d_in[2];
    const float* b1  = (const float*)d_in[3];
    const float* g1  = (const float*)d_in[4];
    const float* be1 = (const float*)d_in[5];
    const float* W2  = (const float*)d_in[6];
    const float* b2  = (const float*)d_in[7];
    const float* g2  = (const float*)d_in[8];
    const float* be2 = (const float*)d_in[9];
    const float* W3  = (const float*)d_in[10];
    const float* b3  = (const float*)d_in[11];
    const float* g3  = (const float*)d_in[12];
    const float* be3 = (const float*)d_in[13];
    const float* W4  = (const float*)d_in[14];
    const float* b4  = (const float*)d_in[15];

    const int N = in_sizes[0] / DH;   // 100000
    const int E = in_sizes[1] / 2;    // 800000
    const int* src = ei;
    const int* dst = ei + E;
    const int nb = (N + 1023) / 1024;

    // workspace layout
    char* w = (char*)d_ws;
    size_t off = 0;
    auto alloc = [&](size_t bytes) { char* p = w + off; off = (off + bytes + 255) & ~(size_t)255; return p; };
    int*    deg      = (int*)alloc((size_t)N * 4);
    int*    rowptr   = (int*)alloc((size_t)(N + 1) * 4);
    int*    blocksum = (int*)alloc(256 * 4);
    int*    blockoff = (int*)alloc(256 * 4);
    float*  dinv     = (float*)alloc((size_t)N * 4);
    double* sums     = (double*)alloc(64);
    float*  scl      = (float*)alloc(64);
    int*    csr_src  = (int*)alloc((size_t)E * 4);
    short*  Wt1      = (short*)alloc((size_t)DH * DH * 2);
    short*  Wt2      = (short*)alloc((size_t)DH * DH * 2);
    short*  Wt3      = (short*)alloc((size_t)DH * DH * 2);
    short*  Wt4      = (short*)alloc((size_t)DZ * DH * 2);
    short*  actbf    = (short*)alloc((size_t)N * DH * 2);   // bf16 activations
    float*  h        = (float*)alloc((size_t)N * DH * 4);
    float*  agg      = (float*)alloc((size_t)N * DH * 4);

    // ---- degree, dinv, CSR build ----
    hipMemsetAsync(deg, 0, (size_t)N * 4, stream);
    deg_count_i<<<(E + 255) / 256, 256, 0, stream>>>(dst, deg, E);
    make_dinv<<<(N + 255) / 256, 256, 0, stream>>>(deg, dinv, N);
    scan1<<<nb, 256, 0, stream>>>(deg, rowptr, blocksum, N);
    scan2<<<1, 256, 0, stream>>>(blocksum, blockoff, nb, rowptr + N);
    scan3<<<(N + 255) / 256, 256, 0, stream>>>(rowptr, blockoff, N);
    hipMemsetAsync(deg, 0, (size_t)N * 4, stream);
    csr_fill<<<(E + 255) / 256, 256, 0, stream>>>(src, dst, rowptr, deg, csr_src, E);

    // ---- weight transpose+cast, input cast ----
    wt_cast<<<(DH * DH + 255) / 256, 256, 0, stream>>>(W1, Wt1, DH, DH);
    wt_cast<<<(DH * DH + 255) / 256, 256, 0, stream>>>(W2, Wt2, DH, DH);
    wt_cast<<<(DH * DH + 255) / 256, 256, 0, stream>>>(W3, Wt3, DH, DH);
    wt_cast<<<(DH * DZ + 255) / 256, 256, 0, stream>>>(W4, Wt4, DH, DZ);
    cast_bf16<<<(N * DH / 4 + 255) / 256, 256, 0, stream>>>(x, actbf, N * DH / 4);

    const int gmM = (N + 127) / 128;
    auto layer = [&](const short* Wt, const float* b, const float* g, const float* be) {
        gemm_mfma<<<dim3(gmM, DH / 128), 256, 0, stream>>>(actbf, Wt, h, N, DH, DH);
        int gt = N * (DH / 4);
        agg_csr<DH><<<(gt + 255) / 256, 256, 0, stream>>>(h, rowptr, csr_src, dinv, b, agg, N);
        hipMemsetAsync(sums, 0, 2 * sizeof(double), stream);
        ln_reduce<<<1024, 256, 0, stream>>>(agg, sums, gt);
        ln_finalize<<<1, 1, 0, stream>>>(sums, scl, (double)N * DH);
        ln_apply_bf<DH><<<(gt + 255) / 256, 256, 0, stream>>>(agg, g, be, scl, actbf, N);
    };

    layer(Wt1, b1, g1, be1);
    layer(Wt2, b2, g2, be2);
    layer(Wt3, b3, g3, be3);

    // final conv: DH -> DZ, straight to d_out
    gemm_mfma<<<dim3(gmM, DZ / 128), 256, 0, stream>>>(actbf, Wt4, h, N, DH, DZ);
    float* out = (float*)d_out;
    int gtz = N * (DZ / 4);
    agg_csr<DZ><<<(gtz + 255) / 256, 256, 0, stream>>>(h, rowptr, csr_src, dinv, b4, out, N);
}

// Round 4
// 837.089 us; speedup vs baseline: 13.1468x; 1.3067x over previous
//
#include <hip/hip_runtime.h>
#include <math.h>

constexpr int DH  = 256;
constexpr int DZ  = 128;
constexpr float EPS   = 1e-5f;
constexpr float SLOPE = 0.01f;

typedef __attribute__((ext_vector_type(8))) short bf16x8;
typedef __attribute__((ext_vector_type(4))) float f32x4;

__device__ __forceinline__ short f2bf(float f) {
    union { float f; unsigned u; } v; v.f = f;
    unsigned r = v.u + 0x7fffu + ((v.u >> 16) & 1u);   // RNE
    return (short)(r >> 16);
}
__device__ __forceinline__ float bf2f(short s) {
    union { unsigned u; float f; } v;
    v.u = ((unsigned)(unsigned short)s) << 16;
    return v.f;
}

// ---------------------------------------------------------------------------
// degree (int) / dinv
// ---------------------------------------------------------------------------
__global__ void deg_count_i(const int* __restrict__ dst, int* __restrict__ deg, int E) {
    int e = blockIdx.x * blockDim.x + threadIdx.x;
    if (e < E) atomicAdd(&deg[dst[e]], 1);
}

__global__ void make_dinv(const int* __restrict__ deg, float* __restrict__ dinv, int N) {
    int i = blockIdx.x * blockDim.x + threadIdx.x;
    if (i < N) dinv[i] = rsqrtf((float)deg[i] + 1.0f);
}

// ---------------------------------------------------------------------------
// exclusive scan of deg[N] -> rowptr
// ---------------------------------------------------------------------------
__global__ __launch_bounds__(256)
void scan1(const int* __restrict__ deg, int* __restrict__ rowptr,
           int* __restrict__ blocksum, int N) {
    __shared__ int ts[256];
    int base = blockIdx.x * 1024 + threadIdx.x * 4;
    int v[4], s = 0;
#pragma unroll
    for (int i = 0; i < 4; ++i) {
        v[i] = (base + i < N) ? deg[base + i] : 0;
        s += v[i];
    }
    ts[threadIdx.x] = s;
    __syncthreads();
    for (int off = 1; off < 256; off <<= 1) {
        int t = 0;
        if ((int)threadIdx.x >= off) t = ts[threadIdx.x - off];
        __syncthreads();
        if ((int)threadIdx.x >= off) ts[threadIdx.x] += t;
        __syncthreads();
    }
    int run = ts[threadIdx.x] - s;
#pragma unroll
    for (int i = 0; i < 4; ++i) {
        if (base + i < N) rowptr[base + i] = run;
        run += v[i];
    }
    if (threadIdx.x == 255) blocksum[blockIdx.x] = ts[255];
}

__global__ __launch_bounds__(256)
void scan2(const int* __restrict__ blocksum, int* __restrict__ blockoff,
           int nb, int* __restrict__ rowptr_last) {
    __shared__ int ts[256];
    int v = ((int)threadIdx.x < nb) ? blocksum[threadIdx.x] : 0;
    ts[threadIdx.x] = v;
    __syncthreads();
    for (int off = 1; off < 256; off <<= 1) {
        int t = 0;
        if ((int)threadIdx.x >= off) t = ts[threadIdx.x - off];
        __syncthreads();
        if ((int)threadIdx.x >= off) ts[threadIdx.x] += t;
        __syncthreads();
    }
    blockoff[threadIdx.x] = ts[threadIdx.x] - v;
    if (threadIdx.x == 255) *rowptr_last = ts[255];
}

__global__ void scan3(int* __restrict__ rowptr, const int* __restrict__ blockoff, int N) {
    int i = blockIdx.x * blockDim.x + threadIdx.x;
    if (i < N) rowptr[i] += blockoff[i >> 10];
}

__global__ void csr_fill(const int* __restrict__ src, const int* __restrict__ dst,
                         const int* __restrict__ rowptr, int* __restrict__ fill,
                         int* __restrict__ csr_src, int E) {
    int e = blockIdx.x * blockDim.x + threadIdx.x;
    if (e >= E) return;
    int d = dst[e];
    int pos = rowptr[d] + atomicAdd(&fill[d], 1);
    csr_src[pos] = src[e];
}

// ---------------------------------------------------------------------------
// casts
// ---------------------------------------------------------------------------
__global__ void cast_bf16(const float* __restrict__ x, short* __restrict__ y, int n4) {
    int i = blockIdx.x * blockDim.x + threadIdx.x;
    if (i >= n4) return;
    float4 v = ((const float4*)x)[i];
    short4 o;
    o.x = f2bf(v.x); o.y = f2bf(v.y); o.z = f2bf(v.z); o.w = f2bf(v.w);
    ((short4*)y)[i] = o;
}

__global__ void wt_cast(const float* __restrict__ W, short* __restrict__ Wt, int K, int NC) {
    int idx = blockIdx.x * blockDim.x + threadIdx.x;
    if (idx >= K * NC) return;
    int n = idx / K, k = idx % K;
    Wt[idx] = f2bf(W[k * NC + n]);
}

// ---------------------------------------------------------------------------
// bf16 MFMA GEMM: C[M,NC](bf16) = A[M,K](bf16) @ Wt[NC,K]^T
// ---------------------------------------------------------------------------
__global__ __launch_bounds__(256)
void gemm_mfma(const short* __restrict__ A, const short* __restrict__ Bt,
               short* __restrict__ C, int M, int K, int NC) {
    __shared__ short As[128 * 32];
    __shared__ short Bs[128 * 32];
    const int tid  = threadIdx.x;
    const int lane = tid & 63;
    const int w    = tid >> 6;
    const int wm   = w & 1, wn = w >> 1;
    const int bm   = blockIdx.x * 128;
    const int bn   = blockIdx.y * 128;

    const int srow = w * 16 + (lane >> 2);
    const int scol = (lane & 3) * 8;

    const int ga_r0 = (bm + srow      < M) ? bm + srow      : M - 1;
    const int ga_r1 = (bm + srow + 64 < M) ? bm + srow + 64 : M - 1;
    const size_t arow0 = (size_t)ga_r0 * K;
    const size_t arow1 = (size_t)ga_r1 * K;
    const size_t brow0 = (size_t)(bn + srow) * K;
    const size_t brow1 = (size_t)(bn + srow + 64) * K;

    f32x4 acc[4][4];
#pragma unroll
    for (int i = 0; i < 4; ++i)
#pragma unroll
        for (int j = 0; j < 4; ++j) acc[i][j] = (f32x4){0.f, 0.f, 0.f, 0.f};

    const int frow = lane & 15;
    const int kg   = (lane >> 4) * 8;

    for (int k0 = 0; k0 < K; k0 += 32) {
        __syncthreads();
        __builtin_amdgcn_global_load_lds(
            (const __attribute__((address_space(1))) void*)(A + arow0 + k0 + scol),
            (__attribute__((address_space(3))) void*)&As[srow * 32 + scol], 16, 0, 0);
        __builtin_amdgcn_global_load_lds(
            (const __attribute__((address_space(1))) void*)(A + arow1 + k0 + scol),
            (__attribute__((address_space(3))) void*)&As[(srow + 64) * 32 + scol], 16, 0, 0);
        __builtin_amdgcn_global_load_lds(
            (const __attribute__((address_space(1))) void*)(Bt + brow0 + k0 + scol),
            (__attribute__((address_space(3))) void*)&Bs[srow * 32 + scol], 16, 0, 0);
        __builtin_amdgcn_global_load_lds(
            (const __attribute__((address_space(1))) void*)(Bt + brow1 + k0 + scol),
            (__attribute__((address_space(3))) void*)&Bs[(srow + 64) * 32 + scol], 16, 0, 0);
        __syncthreads();

        bf16x8 af[4], bf[4];
#pragma unroll
        for (int i = 0; i < 4; ++i)
            af[i] = *(const bf16x8*)&As[(wm * 64 + i * 16 + frow) * 32 + kg];
#pragma unroll
        for (int j = 0; j < 4; ++j)
            bf[j] = *(const bf16x8*)&Bs[(wn * 64 + j * 16 + frow) * 32 + kg];
#pragma unroll
        for (int i = 0; i < 4; ++i)
#pragma unroll
            for (int j = 0; j < 4; ++j)
                acc[i][j] = __builtin_amdgcn_mfma_f32_16x16x32_bf16(
                    af[i], bf[j], acc[i][j], 0, 0, 0);
    }

    const int row_base = bm + wm * 64 + (lane >> 4) * 4;
    const int col_base = bn + wn * 64 + (lane & 15);
#pragma unroll
    for (int i = 0; i < 4; ++i) {
#pragma unroll
        for (int r = 0; r < 4; ++r) {
            int row = row_base + i * 16 + r;
            if (row < M) {
                short* cp = C + (size_t)row * NC + col_base;
#pragma unroll
                for (int j = 0; j < 4; ++j) cp[j * 16] = f2bf(acc[i][j][r]);
            }
        }
    }
}

// ---------------------------------------------------------------------------
// CSR aggregation (bf16 gather, fp32 accumulate) + fused LN partial stats.
// D=256: 64 lanes/node, 4 ch/lane. Writes agg bf16 + per-block (sum,sumsq).
// ---------------------------------------------------------------------------
__global__ __launch_bounds__(256)
void agg_ln_csr(const short* __restrict__ h, const int* __restrict__ rowptr,
                const int* __restrict__ csr_src, const float* __restrict__ dinv,
                const float* __restrict__ bias, short* __restrict__ agg,
                float* __restrict__ psum, float* __restrict__ psumsq, int N) {
    constexpr int TPN = 64;
    int t = blockIdx.x * 256 + threadIdx.x;
    int n = t / TPN, l = t % TPN;
    float4 acc = make_float4(0.f, 0.f, 0.f, 0.f);
    if (n < N) {
        const short4* h4 = (const short4*)h;
        float di = dinv[n];
        float s2 = di * di;
        short4 sv = h4[(size_t)n * TPN + l];
        float4 b = ((const float4*)bias)[l];
        acc.x = bf2f(sv.x) * s2 + b.x;
        acc.y = bf2f(sv.y) * s2 + b.y;
        acc.z = bf2f(sv.z) * s2 + b.z;
        acc.w = bf2f(sv.w) * s2 + b.w;
        int j = rowptr[n], j1 = rowptr[n + 1];
        for (; j + 1 < j1; j += 2) {
            int sA = csr_src[j], sB = csr_src[j + 1];
            float wA = dinv[sA] * di, wB = dinv[sB] * di;
            short4 vA = h4[(size_t)sA * TPN + l];
            short4 vB = h4[(size_t)sB * TPN + l];
            acc.x += bf2f(vA.x) * wA + bf2f(vB.x) * wB;
            acc.y += bf2f(vA.y) * wA + bf2f(vB.y) * wB;
            acc.z += bf2f(vA.z) * wA + bf2f(vB.z) * wB;
            acc.w += bf2f(vA.w) * wA + bf2f(vB.w) * wB;
        }
        if (j < j1) {
            int s = csr_src[j];
            float wgt = dinv[s] * di;
            short4 v = h4[(size_t)s * TPN + l];
            acc.x += bf2f(v.x) * wgt; acc.y += bf2f(v.y) * wgt;
            acc.z += bf2f(v.z) * wgt; acc.w += bf2f(v.w) * wgt;
        }
        short4 o;
        o.x = f2bf(acc.x); o.y = f2bf(acc.y); o.z = f2bf(acc.z); o.w = f2bf(acc.w);
        ((short4*)agg)[(size_t)n * TPN + l] = o;
    }
    // LN partial stats over this block's fp32 accumulators
    float s = acc.x + acc.y + acc.z + acc.w;
    float q = acc.x * acc.x + acc.y * acc.y + acc.z * acc.z + acc.w * acc.w;
#pragma unroll
    for (int off = 32; off; off >>= 1) {
        s += __shfl_down(s, off);
        q += __shfl_down(q, off);
    }
    __shared__ float ss[4], qq[4];
    int wid = threadIdx.x >> 6, lane = threadIdx.x & 63;
    if (lane == 0) { ss[wid] = s; qq[wid] = q; }
    __syncthreads();
    if (threadIdx.x == 0) {
        psum[blockIdx.x]   = ss[0] + ss[1] + ss[2] + ss[3];
        psumsq[blockIdx.x] = qq[0] + qq[1] + qq[2] + qq[3];
    }
}

// final layer: D=128, bf16 gather, fp32 output, no stats
__global__ __launch_bounds__(256)
void agg_out_csr(const short* __restrict__ h, const int* __restrict__ rowptr,
                 const int* __restrict__ csr_src, const float* __restrict__ dinv,
                 const float* __restrict__ bias, float* __restrict__ out, int N) {
    constexpr int TPN = 32;
    int t = blockIdx.x * 256 + threadIdx.x;
    int n = t / TPN, l = t % TPN;
    if (n >= N) return;
    const short4* h4 = (const short4*)h;
    float di = dinv[n];
    float s2 = di * di;
    short4 sv = h4[(size_t)n * TPN + l];
    float4 b = ((const float4*)bias)[l];
    float4 acc;
    acc.x = bf2f(sv.x) * s2 + b.x;
    acc.y = bf2f(sv.y) * s2 + b.y;
    acc.z = bf2f(sv.z) * s2 + b.z;
    acc.w = bf2f(sv.w) * s2 + b.w;
    int j = rowptr[n], j1 = rowptr[n + 1];
    for (; j + 1 < j1; j += 2) {
        int sA = csr_src[j], sB = csr_src[j + 1];
        float wA = dinv[sA] * di, wB = dinv[sB] * di;
        short4 vA = h4[(size_t)sA * TPN + l];
        short4 vB = h4[(size_t)sB * TPN + l];
        acc.x += bf2f(vA.x) * wA + bf2f(vB.x) * wB;
        acc.y += bf2f(vA.y) * wA + bf2f(vB.y) * wB;
        acc.z += bf2f(vA.z) * wA + bf2f(vB.z) * wB;
        acc.w += bf2f(vA.w) * wA + bf2f(vB.w) * wB;
    }
    if (j < j1) {
        int s = csr_src[j];
        float wgt = dinv[s] * di;
        short4 v = h4[(size_t)s * TPN + l];
        acc.x += bf2f(v.x) * wgt; acc.y += bf2f(v.y) * wgt;
        acc.z += bf2f(v.z) * wgt; acc.w += bf2f(v.w) * wgt;
    }
    ((float4*)out)[(size_t)n * TPN + l] = acc;
}

// ---------------------------------------------------------------------------
// LN finalize: reduce per-block partials -> (mean, 1/(std+eps))
// ---------------------------------------------------------------------------
__global__ __launch_bounds__(1024)
void ln_finalize2(const float* __restrict__ psum, const float* __restrict__ psumsq,
                  int nb, float* __restrict__ scl, double M) {
    double s = 0.0, q = 0.0;
    for (int i = threadIdx.x; i < nb; i += 1024) {
        s += (double)psum[i];
        q += (double)psumsq[i];
    }
#pragma unroll
    for (int off = 32; off; off >>= 1) {
        s += __shfl_down(s, off);
        q += __shfl_down(q, off);
    }
    __shared__ double ss[16], qq[16];
    int wid = threadIdx.x >> 6, lane = threadIdx.x & 63;
    if (lane == 0) { ss[wid] = s; qq[wid] = q; }
    __syncthreads();
    if (threadIdx.x == 0) {
        for (int i = 1; i < 16; ++i) { s += ss[i]; q += qq[i]; }
        s += ss[0] - s + s;  // no-op clarity guard
        double mu  = (ss[0] == s ? s : s);  // (kept simple below)
        mu = 0.0;  // recompute cleanly:
        double S = 0.0, Q = 0.0;
        for (int i = 0; i < 16; ++i) { S += ss[i]; Q += qq[i]; }
        mu = S / M;
        double var = Q / M - mu * mu;
        if (var < 0.0) var = 0.0;
        float sd = (float)sqrt(var);
        scl[0] = (float)mu;
        scl[1] = 1.0f / (sd + EPS);
    }
}

// ---------------------------------------------------------------------------
// LN apply + leaky_relu: bf16 in -> bf16 out
// ---------------------------------------------------------------------------
__global__ void ln_apply_bf(const short* __restrict__ x, const float* __restrict__ gamma,
                            const float* __restrict__ beta, const float* __restrict__ scl,
                            short* __restrict__ y, int total4, int D4) {
    int idx = blockIdx.x * blockDim.x + threadIdx.x;
    if (idx >= total4) return;
    float mean = scl[0], inv = scl[1];
    int c4 = (idx % D4) * 4;
    short4 v = ((const short4*)x)[idx];
    float4 g = *(const float4*)(gamma + c4);
    float4 b = *(const float4*)(beta + c4);
    float o0 = (bf2f(v.x) - mean) * inv * g.x + b.x;
    float o1 = (bf2f(v.y) - mean) * inv * g.y + b.y;
    float o2 = (bf2f(v.z) - mean) * inv * g.z + b.z;
    float o3 = (bf2f(v.w) - mean) * inv * g.w + b.w;
    o0 = o0 > 0.f ? o0 : SLOPE * o0;
    o1 = o1 > 0.f ? o1 : SLOPE * o1;
    o2 = o2 > 0.f ? o2 : SLOPE * o2;
    o3 = o3 > 0.f ? o3 : SLOPE * o3;
    short4 o;
    o.x = f2bf(o0); o.y = f2bf(o1); o.z = f2bf(o2); o.w = f2bf(o3);
    ((short4*)y)[idx] = o;
}

// ---------------------------------------------------------------------------
// launcher
// ---------------------------------------------------------------------------
extern "C" void kernel_launch(void* const* d_in, const int* in_sizes, int n_in,
                              void* d_out, int out_size, void* d_ws, size_t ws_size,
                              hipStream_t stream) {
    const float* x   = (const float*)d_in[0];
    const int*   ei  = (const int*)d_in[1];
    const float* W1  = (const float*)d_in[2];
    const float* b1  = (const float*)d_in[3];
    const float* g1  = (const float*)d_in[4];
    const float* be1 = (const float*)d_in[5];
    const float* W2  = (const float*)d_in[6];
    const float* b2  = (const float*)d_in[7];
    const float* g2  = (const float*)d_in[8];
    const float* be2 = (const float*)d_in[9];
    const float* W3  = (const float*)d_in[10];
    const float* b3  = (const float*)d_in[11];
    const float* g3  = (const float*)d_in[12];
    const float* be3 = (const float*)d_in[13];
    const float* W4  = (const float*)d_in[14];
    const float* b4  = (const float*)d_in[15];

    const int N = in_sizes[0] / DH;   // 100000
    const int E = in_sizes[1] / 2;    // 800000
    const int* src = ei;
    const int* dst = ei + E;
    const int nb = (N + 1023) / 1024;
    const int nagg = (N * 64 + 255) / 256;   // agg_ln_csr blocks (25000)

    char* w = (char*)d_ws;
    size_t off = 0;
    auto alloc = [&](size_t bytes) { char* p = w + off; off = (off + bytes + 255) & ~(size_t)255; return p; };
    int*    deg      = (int*)alloc((size_t)N * 4);
    int*    rowptr   = (int*)alloc((size_t)(N + 1) * 4);
    int*    blocksum = (int*)alloc(256 * 4);
    int*    blockoff = (int*)alloc(256 * 4);
    float*  dinv     = (float*)alloc((size_t)N * 4);
    float*  scl      = (float*)alloc(64);
    float*  psum     = (float*)alloc((size_t)nagg * 4);
    float*  psumsq   = (float*)alloc((size_t)nagg * 4);
    int*    csr_src  = (int*)alloc((size_t)E * 4);
    short*  Wt1      = (short*)alloc((size_t)DH * DH * 2);
    short*  Wt2      = (short*)alloc((size_t)DH * DH * 2);
    short*  Wt3      = (short*)alloc((size_t)DH * DH * 2);
    short*  Wt4      = (short*)alloc((size_t)DZ * DH * 2);
    short*  actbf    = (short*)alloc((size_t)N * DH * 2);
    short*  hbf      = (short*)alloc((size_t)N * DH * 2);
    short*  aggb     = (short*)alloc((size_t)N * DH * 2);

    // ---- degree, dinv, CSR build ----
    hipMemsetAsync(deg, 0, (size_t)N * 4, stream);
    deg_count_i<<<(E + 255) / 256, 256, 0, stream>>>(dst, deg, E);
    make_dinv<<<(N + 255) / 256, 256, 0, stream>>>(deg, dinv, N);
    scan1<<<nb, 256, 0, stream>>>(deg, rowptr, blocksum, N);
    scan2<<<1, 256, 0, stream>>>(blocksum, blockoff, nb, rowptr + N);
    scan3<<<(N + 255) / 256, 256, 0, stream>>>(rowptr, blockoff, N);
    hipMemsetAsync(deg, 0, (size_t)N * 4, stream);
    csr_fill<<<(E + 255) / 256, 256, 0, stream>>>(src, dst, rowptr, deg, csr_src, E);

    // ---- weight transpose+cast, input cast ----
    wt_cast<<<(DH * DH + 255) / 256, 256, 0, stream>>>(W1, Wt1, DH, DH);
    wt_cast<<<(DH * DH + 255) / 256, 256, 0, stream>>>(W2, Wt2, DH, DH);
    wt_cast<<<(DH * DH + 255) / 256, 256, 0, stream>>>(W3, Wt3, DH, DH);
    wt_cast<<<(DH * DZ + 255) / 256, 256, 0, stream>>>(W4, Wt4, DH, DZ);
    cast_bf16<<<(N * DH / 4 + 255) / 256, 256, 0, stream>>>(x, actbf, N * DH / 4);

    const int gmM = (N + 127) / 128;
    auto layer = [&](const short* Wt, const float* b, const float* g, const float* be) {
        gemm_mfma<<<dim3(gmM, DH / 128), 256, 0, stream>>>(actbf, Wt, hbf, N, DH, DH);
        agg_ln_csr<<<nagg, 256, 0, stream>>>(hbf, rowptr, csr_src, dinv, b, aggb,
                                             psum, psumsq, N);
        ln_finalize2<<<1, 1024, 0, stream>>>(psum, psumsq, nagg, scl, (double)N * DH);
        int t4 = N * (DH / 4);
        ln_apply_bf<<<(t4 + 255) / 256, 256, 0, stream>>>(aggb, g, be, scl, actbf,
                                                          t4, DH / 4);
    };

    layer(Wt1, b1, g1, be1);
    layer(Wt2, b2, g2, be2);
    layer(Wt3, b3, g3, be3);

    // final conv: DH -> DZ
    gemm_mfma<<<dim3(gmM, DZ / 128), 256, 0, stream>>>(actbf, Wt4, hbf, N, DH, DZ);
    float* out = (float*)d_out;
    int naggz = (N * 32 + 255) / 256;
    agg_out_csr<<<naggz, 256, 0, stream>>>(hbf, rowptr, csr_src, dinv, b4, out, N);
}

// Round 5
// 731.461 us; speedup vs baseline: 15.0453x; 1.1444x over previous
//
#include <hip/hip_runtime.h>
#include <math.h>

constexpr int DH  = 256;
constexpr int DZ  = 128;
constexpr float EPS   = 1e-5f;
constexpr float SLOPE = 0.01f;

typedef __attribute__((ext_vector_type(8))) short bf16x8;
typedef __attribute__((ext_vector_type(4))) float f32x4;

__device__ __forceinline__ short f2bf(float f) {
    union { float f; unsigned u; } v; v.f = f;
    unsigned r = v.u + 0x7fffu + ((v.u >> 16) & 1u);   // RNE
    return (short)(r >> 16);
}
__device__ __forceinline__ float bf2f(short s) {
    union { unsigned u; float f; } v;
    v.u = ((unsigned)(unsigned short)s) << 16;
    return v.f;
}

// ---------------------------------------------------------------------------
// degree (int) / dinv
// ---------------------------------------------------------------------------
__global__ void deg_count_i(const int* __restrict__ dst, int* __restrict__ deg, int E) {
    int e = blockIdx.x * blockDim.x + threadIdx.x;
    if (e < E) atomicAdd(&deg[dst[e]], 1);
}

__global__ void make_dinv(const int* __restrict__ deg, float* __restrict__ dinv, int N) {
    int i = blockIdx.x * blockDim.x + threadIdx.x;
    if (i < N) dinv[i] = rsqrtf((float)deg[i] + 1.0f);
}

// ---------------------------------------------------------------------------
// exclusive scan of deg[N] -> rowptr
// ---------------------------------------------------------------------------
__global__ __launch_bounds__(256)
void scan1(const int* __restrict__ deg, int* __restrict__ rowptr,
           int* __restrict__ blocksum, int N) {
    __shared__ int ts[256];
    int base = blockIdx.x * 1024 + threadIdx.x * 4;
    int v[4], s = 0;
#pragma unroll
    for (int i = 0; i < 4; ++i) {
        v[i] = (base + i < N) ? deg[base + i] : 0;
        s += v[i];
    }
    ts[threadIdx.x] = s;
    __syncthreads();
    for (int off = 1; off < 256; off <<= 1) {
        int t = 0;
        if ((int)threadIdx.x >= off) t = ts[threadIdx.x - off];
        __syncthreads();
        if ((int)threadIdx.x >= off) ts[threadIdx.x] += t;
        __syncthreads();
    }
    int run = ts[threadIdx.x] - s;
#pragma unroll
    for (int i = 0; i < 4; ++i) {
        if (base + i < N) rowptr[base + i] = run;
        run += v[i];
    }
    if (threadIdx.x == 255) blocksum[blockIdx.x] = ts[255];
}

__global__ __launch_bounds__(256)
void scan2(const int* __restrict__ blocksum, int* __restrict__ blockoff,
           int nb, int* __restrict__ rowptr_last) {
    __shared__ int ts[256];
    int v = ((int)threadIdx.x < nb) ? blocksum[threadIdx.x] : 0;
    ts[threadIdx.x] = v;
    __syncthreads();
    for (int off = 1; off < 256; off <<= 1) {
        int t = 0;
        if ((int)threadIdx.x >= off) t = ts[threadIdx.x - off];
        __syncthreads();
        if ((int)threadIdx.x >= off) ts[threadIdx.x] += t;
        __syncthreads();
    }
    blockoff[threadIdx.x] = ts[threadIdx.x] - v;
    if (threadIdx.x == 255) *rowptr_last = ts[255];
}

__global__ void scan3(int* __restrict__ rowptr, const int* __restrict__ blockoff, int N) {
    int i = blockIdx.x * blockDim.x + threadIdx.x;
    if (i < N) rowptr[i] += blockoff[i >> 10];
}

__global__ void csr_fill(const int* __restrict__ src, const int* __restrict__ dst,
                         const int* __restrict__ rowptr, int* __restrict__ fill,
                         int* __restrict__ csr_src, int E) {
    int e = blockIdx.x * blockDim.x + threadIdx.x;
    if (e >= E) return;
    int d = dst[e];
    int pos = rowptr[d] + atomicAdd(&fill[d], 1);
    csr_src[pos] = src[e];
}

// ---------------------------------------------------------------------------
// casts
// ---------------------------------------------------------------------------
__global__ void cast_bf16(const float* __restrict__ x, short* __restrict__ y, int n4) {
    int i = blockIdx.x * blockDim.x + threadIdx.x;
    if (i >= n4) return;
    float4 v = ((const float4*)x)[i];
    short4 o;
    o.x = f2bf(v.x); o.y = f2bf(v.y); o.z = f2bf(v.z); o.w = f2bf(v.w);
    ((short4*)y)[i] = o;
}

__global__ void wt_cast(const float* __restrict__ W, short* __restrict__ Wt, int K, int NC) {
    int idx = blockIdx.x * blockDim.x + threadIdx.x;
    if (idx >= K * NC) return;
    int n = idx / K, k = idx % K;
    Wt[idx] = f2bf(W[k * NC + n]);
}

// ---------------------------------------------------------------------------
// bf16 MFMA GEMM: C[M,NC](bf16) = A[M,K](bf16) @ Wt[NC,K]^T
// ---------------------------------------------------------------------------
__global__ __launch_bounds__(256)
void gemm_mfma(const short* __restrict__ A, const short* __restrict__ Bt,
               short* __restrict__ C, int M, int K, int NC) {
    __shared__ short As[128 * 32];
    __shared__ short Bs[128 * 32];
    const int tid  = threadIdx.x;
    const int lane = tid & 63;
    const int w    = tid >> 6;
    const int wm   = w & 1, wn = w >> 1;
    const int bm   = blockIdx.x * 128;
    const int bn   = blockIdx.y * 128;

    const int srow = w * 16 + (lane >> 2);
    const int scol = (lane & 3) * 8;

    const int ga_r0 = (bm + srow      < M) ? bm + srow      : M - 1;
    const int ga_r1 = (bm + srow + 64 < M) ? bm + srow + 64 : M - 1;
    const size_t arow0 = (size_t)ga_r0 * K;
    const size_t arow1 = (size_t)ga_r1 * K;
    const size_t brow0 = (size_t)(bn + srow) * K;
    const size_t brow1 = (size_t)(bn + srow + 64) * K;

    f32x4 acc[4][4];
#pragma unroll
    for (int i = 0; i < 4; ++i)
#pragma unroll
        for (int j = 0; j < 4; ++j) acc[i][j] = (f32x4){0.f, 0.f, 0.f, 0.f};

    const int frow = lane & 15;
    const int kg   = (lane >> 4) * 8;

    for (int k0 = 0; k0 < K; k0 += 32) {
        __syncthreads();
        __builtin_amdgcn_global_load_lds(
            (const __attribute__((address_space(1))) void*)(A + arow0 + k0 + scol),
            (__attribute__((address_space(3))) void*)&As[srow * 32 + scol], 16, 0, 0);
        __builtin_amdgcn_global_load_lds(
            (const __attribute__((address_space(1))) void*)(A + arow1 + k0 + scol),
            (__attribute__((address_space(3))) void*)&As[(srow + 64) * 32 + scol], 16, 0, 0);
        __builtin_amdgcn_global_load_lds(
            (const __attribute__((address_space(1))) void*)(Bt + brow0 + k0 + scol),
            (__attribute__((address_space(3))) void*)&Bs[srow * 32 + scol], 16, 0, 0);
        __builtin_amdgcn_global_load_lds(
            (const __attribute__((address_space(1))) void*)(Bt + brow1 + k0 + scol),
            (__attribute__((address_space(3))) void*)&Bs[(srow + 64) * 32 + scol], 16, 0, 0);
        __syncthreads();

        bf16x8 af[4], bfr[4];
#pragma unroll
        for (int i = 0; i < 4; ++i)
            af[i] = *(const bf16x8*)&As[(wm * 64 + i * 16 + frow) * 32 + kg];
#pragma unroll
        for (int j = 0; j < 4; ++j)
            bfr[j] = *(const bf16x8*)&Bs[(wn * 64 + j * 16 + frow) * 32 + kg];
#pragma unroll
        for (int i = 0; i < 4; ++i)
#pragma unroll
            for (int j = 0; j < 4; ++j)
                acc[i][j] = __builtin_amdgcn_mfma_f32_16x16x32_bf16(
                    af[i], bfr[j], acc[i][j], 0, 0, 0);
    }

    const int row_base = bm + wm * 64 + (lane >> 4) * 4;
    const int col_base = bn + wn * 64 + (lane & 15);
#pragma unroll
    for (int i = 0; i < 4; ++i) {
#pragma unroll
        for (int r = 0; r < 4; ++r) {
            int row = row_base + i * 16 + r;
            if (row < M) {
                short* cp = C + (size_t)row * NC + col_base;
#pragma unroll
                for (int j = 0; j < 4; ++j) cp[j * 16] = f2bf(acc[i][j][r]);
            }
        }
    }
}

// ---------------------------------------------------------------------------
// CSR aggregation (bf16 gather, fp32 acc) + fused LN partial stats.
// D=256: 32 lanes/node (16B=short8 per lane), 2 nodes/wave, edge loop 4x
// unrolled -> up to 8 independent 512B gathers in flight per wave.
// ---------------------------------------------------------------------------
__global__ __launch_bounds__(256)
void agg_ln_csr(const short* __restrict__ h, const int* __restrict__ rowptr,
                const int* __restrict__ csr_src, const float* __restrict__ dinv,
                const float* __restrict__ bias, short* __restrict__ agg,
                float* __restrict__ psum, float* __restrict__ psumsq, int N) {
    constexpr int TPN = 32;                 // D=256 bf16 -> 32 x 16B
    int t = blockIdx.x * 256 + threadIdx.x;
    int n = t / TPN, l = t % TPN;
    float acc[8] = {0.f, 0.f, 0.f, 0.f, 0.f, 0.f, 0.f, 0.f};
    if (n < N) {
        const bf16x8* h8 = (const bf16x8*)h;   // row = 32 vectors
        float di = dinv[n];
        float sl2 = di * di;
        bf16x8 sv = h8[(size_t)n * TPN + l];
        const float* bp = bias + l * 8;
#pragma unroll
        for (int c = 0; c < 8; ++c) acc[c] = bf2f(sv[c]) * sl2 + bp[c];
        int j = rowptr[n], j1 = rowptr[n + 1];
        for (; j + 3 < j1; j += 4) {
            int i0 = csr_src[j], i1 = csr_src[j + 1];
            int i2 = csr_src[j + 2], i3 = csr_src[j + 3];
            float w0 = dinv[i0] * di, w1 = dinv[i1] * di;
            float w2 = dinv[i2] * di, w3 = dinv[i3] * di;
            bf16x8 v0 = h8[(size_t)i0 * TPN + l];
            bf16x8 v1 = h8[(size_t)i1 * TPN + l];
            bf16x8 v2 = h8[(size_t)i2 * TPN + l];
            bf16x8 v3 = h8[(size_t)i3 * TPN + l];
#pragma unroll
            for (int c = 0; c < 8; ++c)
                acc[c] += bf2f(v0[c]) * w0 + bf2f(v1[c]) * w1 +
                          bf2f(v2[c]) * w2 + bf2f(v3[c]) * w3;
        }
        if (j + 1 < j1) {
            int i0 = csr_src[j], i1 = csr_src[j + 1];
            float w0 = dinv[i0] * di, w1 = dinv[i1] * di;
            bf16x8 v0 = h8[(size_t)i0 * TPN + l];
            bf16x8 v1 = h8[(size_t)i1 * TPN + l];
#pragma unroll
            for (int c = 0; c < 8; ++c)
                acc[c] += bf2f(v0[c]) * w0 + bf2f(v1[c]) * w1;
            j += 2;
        }
        if (j < j1) {
            int i0 = csr_src[j];
            float w0 = dinv[i0] * di;
            bf16x8 v0 = h8[(size_t)i0 * TPN + l];
#pragma unroll
            for (int c = 0; c < 8; ++c) acc[c] += bf2f(v0[c]) * w0;
        }
        bf16x8 o;
#pragma unroll
        for (int c = 0; c < 8; ++c) o[c] = f2bf(acc[c]);
        ((bf16x8*)agg)[(size_t)n * TPN + l] = o;
    }
    // LN partial stats
    float s = 0.f, q = 0.f;
#pragma unroll
    for (int c = 0; c < 8; ++c) { s += acc[c]; q += acc[c] * acc[c]; }
#pragma unroll
    for (int off = 32; off; off >>= 1) {
        s += __shfl_down(s, off);
        q += __shfl_down(q, off);
    }
    __shared__ float ss[4], qq[4];
    int wid = threadIdx.x >> 6, lane = threadIdx.x & 63;
    if (lane == 0) { ss[wid] = s; qq[wid] = q; }
    __syncthreads();
    if (threadIdx.x == 0) {
        psum[blockIdx.x]   = ss[0] + ss[1] + ss[2] + ss[3];
        psumsq[blockIdx.x] = qq[0] + qq[1] + qq[2] + qq[3];
    }
}

// final layer: D=128, 16 lanes/node (16B), 4 nodes/wave, fp32 out, no stats
__global__ __launch_bounds__(256)
void agg_out_csr(const short* __restrict__ h, const int* __restrict__ rowptr,
                 const int* __restrict__ csr_src, const float* __restrict__ dinv,
                 const float* __restrict__ bias, float* __restrict__ out, int N) {
    constexpr int TPN = 16;                 // D=128 bf16 -> 16 x 16B
    int t = blockIdx.x * 256 + threadIdx.x;
    int n = t / TPN, l = t % TPN;
    if (n >= N) return;
    const bf16x8* h8 = (const bf16x8*)h;
    float di = dinv[n];
    float sl2 = di * di;
    bf16x8 sv = h8[(size_t)n * TPN + l];
    const float* bp = bias + l * 8;
    float acc[8];
#pragma unroll
    for (int c = 0; c < 8; ++c) acc[c] = bf2f(sv[c]) * sl2 + bp[c];
    int j = rowptr[n], j1 = rowptr[n + 1];
    for (; j + 3 < j1; j += 4) {
        int i0 = csr_src[j], i1 = csr_src[j + 1];
        int i2 = csr_src[j + 2], i3 = csr_src[j + 3];
        float w0 = dinv[i0] * di, w1 = dinv[i1] * di;
        float w2 = dinv[i2] * di, w3 = dinv[i3] * di;
        bf16x8 v0 = h8[(size_t)i0 * TPN + l];
        bf16x8 v1 = h8[(size_t)i1 * TPN + l];
        bf16x8 v2 = h8[(size_t)i2 * TPN + l];
        bf16x8 v3 = h8[(size_t)i3 * TPN + l];
#pragma unroll
        for (int c = 0; c < 8; ++c)
            acc[c] += bf2f(v0[c]) * w0 + bf2f(v1[c]) * w1 +
                      bf2f(v2[c]) * w2 + bf2f(v3[c]) * w3;
    }
    if (j + 1 < j1) {
        int i0 = csr_src[j], i1 = csr_src[j + 1];
        float w0 = dinv[i0] * di, w1 = dinv[i1] * di;
        bf16x8 v0 = h8[(size_t)i0 * TPN + l];
        bf16x8 v1 = h8[(size_t)i1 * TPN + l];
#pragma unroll
        for (int c = 0; c < 8; ++c)
            acc[c] += bf2f(v0[c]) * w0 + bf2f(v1[c]) * w1;
        j += 2;
    }
    if (j < j1) {
        int i0 = csr_src[j];
        float w0 = dinv[i0] * di;
        bf16x8 v0 = h8[(size_t)i0 * TPN + l];
#pragma unroll
        for (int c = 0; c < 8; ++c) acc[c] += bf2f(v0[c]) * w0;
    }
    float4* op = (float4*)(out + (size_t)n * 128 + l * 8);
    op[0] = make_float4(acc[0], acc[1], acc[2], acc[3]);
    op[1] = make_float4(acc[4], acc[5], acc[6], acc[7]);
}

// ---------------------------------------------------------------------------
// LN finalize: reduce per-block partials -> (mean, 1/(std+eps))
// ---------------------------------------------------------------------------
__global__ __launch_bounds__(1024)
void ln_finalize2(const float* __restrict__ psum, const float* __restrict__ psumsq,
                  int nb, float* __restrict__ scl, double M) {
    double s = 0.0, q = 0.0;
    for (int i = threadIdx.x; i < nb; i += 1024) {
        s += (double)psum[i];
        q += (double)psumsq[i];
    }
#pragma unroll
    for (int off = 32; off; off >>= 1) {
        s += __shfl_down(s, off);
        q += __shfl_down(q, off);
    }
    __shared__ double ss[16], qq[16];
    int wid = threadIdx.x >> 6, lane = threadIdx.x & 63;
    if (lane == 0) { ss[wid] = s; qq[wid] = q; }
    __syncthreads();
    if (threadIdx.x == 0) {
        double S = 0.0, Q = 0.0;
        for (int i = 0; i < 16; ++i) { S += ss[i]; Q += qq[i]; }
        double mu  = S / M;
        double var = Q / M - mu * mu;
        if (var < 0.0) var = 0.0;
        float sd = (float)sqrt(var);
        scl[0] = (float)mu;
        scl[1] = 1.0f / (sd + EPS);
    }
}

// ---------------------------------------------------------------------------
// LN apply + leaky_relu: bf16 in -> bf16 out
// ---------------------------------------------------------------------------
__global__ void ln_apply_bf(const short* __restrict__ x, const float* __restrict__ gamma,
                            const float* __restrict__ beta, const float* __restrict__ scl,
                            short* __restrict__ y, int total4, int D4) {
    int idx = blockIdx.x * blockDim.x + threadIdx.x;
    if (idx >= total4) return;
    float mean = scl[0], inv = scl[1];
    int c4 = (idx % D4) * 4;
    short4 v = ((const short4*)x)[idx];
    float4 g = *(const float4*)(gamma + c4);
    float4 b = *(const float4*)(beta + c4);
    float o0 = (bf2f(v.x) - mean) * inv * g.x + b.x;
    float o1 = (bf2f(v.y) - mean) * inv * g.y + b.y;
    float o2 = (bf2f(v.z) - mean) * inv * g.z + b.z;
    float o3 = (bf2f(v.w) - mean) * inv * g.w + b.w;
    o0 = o0 > 0.f ? o0 : SLOPE * o0;
    o1 = o1 > 0.f ? o1 : SLOPE * o1;
    o2 = o2 > 0.f ? o2 : SLOPE * o2;
    o3 = o3 > 0.f ? o3 : SLOPE * o3;
    short4 o;
    o.x = f2bf(o0); o.y = f2bf(o1); o.z = f2bf(o2); o.w = f2bf(o3);
    ((short4*)y)[idx] = o;
}

// ---------------------------------------------------------------------------
// launcher
// ---------------------------------------------------------------------------
extern "C" void kernel_launch(void* const* d_in, const int* in_sizes, int n_in,
                              void* d_out, int out_size, void* d_ws, size_t ws_size,
                              hipStream_t stream) {
    const float* x   = (const float*)d_in[0];
    const int*   ei  = (const int*)d_in[1];
    const float* W1  = (const float*)d_in[2];
    const float* b1  = (const float*)d_in[3];
    const float* g1  = (const float*)d_in[4];
    const float* be1 = (const float*)d_in[5];
    const float* W2  = (const float*)d_in[6];
    const float* b2  = (const float*)d_in[7];
    const float* g2  = (const float*)d_in[8];
    const float* be2 = (const float*)d_in[9];
    const float* W3  = (const float*)d_in[10];
    const float* b3  = (const float*)d_in[11];
    const float* g3  = (const float*)d_in[12];
    const float* be3 = (const float*)d_in[13];
    const float* W4  = (const float*)d_in[14];
    const float* b4  = (const float*)d_in[15];

    const int N = in_sizes[0] / DH;   // 100000
    const int E = in_sizes[1] / 2;    // 800000
    const int* src = ei;
    const int* dst = ei + E;
    const int nb = (N + 1023) / 1024;
    const int nagg = (N * 32 + 255) / 256;   // agg_ln_csr blocks (12500)

    char* w = (char*)d_ws;
    size_t off = 0;
    auto alloc = [&](size_t bytes) { char* p = w + off; off = (off + bytes + 255) & ~(size_t)255; return p; };
    int*    deg      = (int*)alloc((size_t)N * 4);
    int*    rowptr   = (int*)alloc((size_t)(N + 1) * 4);
    int*    blocksum = (int*)alloc(256 * 4);
    int*    blockoff = (int*)alloc(256 * 4);
    float*  dinv     = (float*)alloc((size_t)N * 4);
    float*  scl      = (float*)alloc(64);
    float*  psum     = (float*)alloc((size_t)nagg * 4);
    float*  psumsq   = (float*)alloc((size_t)nagg * 4);
    int*    csr_src  = (int*)alloc((size_t)E * 4);
    short*  Wt1      = (short*)alloc((size_t)DH * DH * 2);
    short*  Wt2      = (short*)alloc((size_t)DH * DH * 2);
    short*  Wt3      = (short*)alloc((size_t)DH * DH * 2);
    short*  Wt4      = (short*)alloc((size_t)DZ * DH * 2);
    short*  actbf    = (short*)alloc((size_t)N * DH * 2);
    short*  hbf      = (short*)alloc((size_t)N * DH * 2);
    short*  aggb     = (short*)alloc((size_t)N * DH * 2);

    // ---- degree, dinv, CSR build ----
    hipMemsetAsync(deg, 0, (size_t)N * 4, stream);
    deg_count_i<<<(E + 255) / 256, 256, 0, stream>>>(dst, deg, E);
    make_dinv<<<(N + 255) / 256, 256, 0, stream>>>(deg, dinv, N);
    scan1<<<nb, 256, 0, stream>>>(deg, rowptr, blocksum, N);
    scan2<<<1, 256, 0, stream>>>(blocksum, blockoff, nb, rowptr + N);
    scan3<<<(N + 255) / 256, 256, 0, stream>>>(rowptr, blockoff, N);
    hipMemsetAsync(deg, 0, (size_t)N * 4, stream);
    csr_fill<<<(E + 255) / 256, 256, 0, stream>>>(src, dst, rowptr, deg, csr_src, E);

    // ---- weight transpose+cast, input cast ----
    wt_cast<<<(DH * DH + 255) / 256, 256, 0, stream>>>(W1, Wt1, DH, DH);
    wt_cast<<<(DH * DH + 255) / 256, 256, 0, stream>>>(W2, Wt2, DH, DH);
    wt_cast<<<(DH * DH + 255) / 256, 256, 0, stream>>>(W3, Wt3, DH, DH);
    wt_cast<<<(DH * DZ + 255) / 256, 256, 0, stream>>>(W4, Wt4, DH, DZ);
    cast_bf16<<<(N * DH / 4 + 255) / 256, 256, 0, stream>>>(x, actbf, N * DH / 4);

    const int gmM = (N + 127) / 128;
    auto layer = [&](const short* Wt, const float* b, const float* g, const float* be) {
        gemm_mfma<<<dim3(gmM, DH / 128), 256, 0, stream>>>(actbf, Wt, hbf, N, DH, DH);
        agg_ln_csr<<<nagg, 256, 0, stream>>>(hbf, rowptr, csr_src, dinv, b, aggb,
                                             psum, psumsq, N);
        ln_finalize2<<<1, 1024, 0, stream>>>(psum, psumsq, nagg, scl, (double)N * DH);
        int t4 = N * (DH / 4);
        ln_apply_bf<<<(t4 + 255) / 256, 256, 0, stream>>>(aggb, g, be, scl, actbf,
                                                          t4, DH / 4);
    };

    layer(Wt1, b1, g1, be1);
    layer(Wt2, b2, g2, be2);
    layer(Wt3, b3, g3, be3);

    // final conv: DH -> DZ
    gemm_mfma<<<dim3(gmM, DZ / 128), 256, 0, stream>>>(actbf, Wt4, hbf, N, DH, DZ);
    float* out = (float*)d_out;
    int naggz = (N * 16 + 255) / 256;
    agg_out_csr<<<naggz, 256, 0, stream>>>(hbf, rowptr, csr_src, dinv, b4, out, N);
}